// Round 4
// baseline (236.842 us; speedup 1.0000x reference)
//
#include <hip/hip_runtime.h>
#include <hip/hip_bf16.h>
#include <cstdint>

// bf16 fragments as 8 x short (4 VGPRs) per cdna_hip_programming.md §3
typedef __attribute__((ext_vector_type(8))) short bf16x8;
typedef __attribute__((ext_vector_type(4))) float f32x4;
typedef __attribute__((ext_vector_type(16))) float f32x16;
typedef __attribute__((ext_vector_type(4))) uint16_t u16x4;

__device__ __forceinline__ uint16_t f2b(float f) {
  union { float f; uint32_t i; } v; v.f = f;
  return (uint16_t)((v.i + 0x7FFFu + ((v.i >> 16) & 1u)) >> 16);  // RNE
}

__device__ __forceinline__ uint32_t pkbf(float a, float b) {
  union { __hip_bfloat162 h2; uint32_t u; } c;
  c.h2 = __float22bfloat162_rn(make_float2(a, b));
  return c.u;   // low16 = a, high16 = b
}

// async global->LDS, 16B per lane; LDS dest is wave-uniform base + lane*16
#define GLDS16(g, l) __builtin_amdgcn_global_load_lds( \
    (const __attribute__((address_space(1))) void*)(g), \
    (__attribute__((address_space(3))) void*)(l), 16, 0, 0)

// ---------------------------------------------------------------------------
// fp32 -> bf16 convert (RNE) for all three inputs in one launch
// ---------------------------------------------------------------------------
__global__ __launch_bounds__(256) void cvt_all(
    const float* __restrict__ x, const float* __restrict__ wa, const float* __restrict__ wp,
    uint16_t* __restrict__ xb, uint16_t* __restrict__ wab, uint16_t* __restrict__ wpb) {
  const int i = (blockIdx.x * 256 + threadIdx.x) * 4;
  const float* src; uint16_t* dst; int off;
  if (i < 4194304)      { src = x;  dst = xb;  off = i; }
  else if (i < 7340032) { src = wa; dst = wab; off = i - 4194304; }
  else                  { src = wp; dst = wpb; off = i - 7340032; }
  const float4 v = *(const float4*)(src + off);
  u16x4 o;
  o.x = f2b(v.x); o.y = f2b(v.y); o.z = f2b(v.z); o.w = f2b(v.w);
  *(u16x4*)(dst + off) = o;
}

// ---------------------------------------------------------------------------
// C[M,N] = A[M,K] @ B[N,K]^T + bias[N]. A,B bf16, bias fp32, fp32 accumulate.
// ---------------------------------------------------------------------------
template <int BM, bool OUT_BF16>
__global__ __launch_bounds__(256) void gemm_bt_bias(
    const uint16_t* __restrict__ A, const uint16_t* __restrict__ B,
    const float* __restrict__ bias, void* __restrict__ Cv,
    int M, int N, int K) {
  constexpr int MI = BM / 32;            // acc rows of 16
  constexpr int CA = BM / 16;            // A chunks per k-half
  constexpr int CPW = (2 * (CA + 8)) / 4;
  constexpr int CT_PITCH = OUT_BF16 ? 72 : 68;
  constexpr size_t CT_BYTES = (size_t)4 * (BM / 2) * CT_PITCH * (OUT_BF16 ? 2 : 4);
  constexpr size_t ST_BYTES = (size_t)(2 * (BM * 32 + 4096)) * 2;
  constexpr size_t LB = CT_BYTES > ST_BYTES ? CT_BYTES : ST_BYTES;
  __shared__ alignas(16) unsigned char ldsb[LB];
  uint16_t* lds = (uint16_t*)ldsb;
  const int offB0 = BM * 32;             // u16 offsets
  const int offA1 = BM * 32 + 4096;
  const int offB1 = 2 * BM * 32 + 4096;

  const int tid = threadIdx.x;
  const int wave = tid >> 6, lane = tid & 63;
  const int q4 = lane >> 4, l16 = lane & 15;
  const int wm = wave >> 1, wn = wave & 1;
  const long blockM = (long)blockIdx.y * BM;
  const long blockN = (long)blockIdx.x * 128;

  f32x4 acc[MI][4] = {};

  for (int k0 = 0; k0 < K; k0 += 64) {
#pragma unroll
    for (int c = 0; c < CPW; ++c) {
      const int id = c * 4 + wave;       // wave-uniform
      const uint16_t* mat; long rowBase; int a, kk, off;
      if (id < CA)               { mat = A; rowBase = blockM; a = id;            kk = k0;      off = 0; }
      else if (id < CA + 8)      { mat = B; rowBase = blockN; a = id - CA;       kk = k0;      off = offB0; }
      else if (id < 2 * CA + 8)  { mat = A; rowBase = blockM; a = id - CA - 8;   kk = k0 + 32; off = offA1; }
      else                       { mat = B; rowBase = blockN; a = id - 2*CA - 8; kk = k0 + 32; off = offB1; }
      const int flat = a * 64 + lane;
      const int row = flat >> 2, seg = flat & 3;
      GLDS16(mat + (rowBase + row) * (long)K + kk + seg * 8, lds + off + a * 512);
    }
    __syncthreads();
#pragma unroll
    for (int h = 0; h < 2; ++h) {
      const uint16_t* Ah = lds + (h ? offA1 : 0);
      const uint16_t* Bh = lds + (h ? offB1 : offB0);
      bf16x8 af[MI], bfr[4];
#pragma unroll
      for (int i = 0; i < MI; ++i)
        af[i] = *(const bf16x8*)&Ah[(wm * (BM / 2) + i * 16 + l16) * 32 + q4 * 8];
#pragma unroll
      for (int j = 0; j < 4; ++j)
        bfr[j] = *(const bf16x8*)&Bh[(wn * 64 + j * 16 + l16) * 32 + q4 * 8];
#pragma unroll
      for (int i = 0; i < MI; ++i)
#pragma unroll
        for (int j = 0; j < 4; ++j)
          acc[i][j] = __builtin_amdgcn_mfma_f32_16x16x32_bf16(af[i], bfr[j], acc[i][j], 0, 0, 0);
    }
    __syncthreads();
  }

  // epilogue: acc (C/D layout: col=l16, row=q4*4+r) -> per-wave LDS tile -> vector stores
  if (OUT_BF16) {
    uint16_t* ct = lds + wave * (BM / 2) * 72;
#pragma unroll
    for (int j = 0; j < 4; ++j) {
      const float bv = bias[blockN + wn * 64 + j * 16 + l16];
#pragma unroll
      for (int i = 0; i < MI; ++i)
#pragma unroll
        for (int r = 0; r < 4; ++r)
          ct[(i * 16 + q4 * 4 + r) * 72 + j * 16 + l16] = f2b(acc[i][j][r] + bv);
    }
    __syncthreads();
    uint16_t* Cb = (uint16_t*)Cv;
#pragma unroll
    for (int st = 0; st < BM / 16; ++st) {
      const int flat = st * 64 + lane;
      const int row = flat >> 3, seg = flat & 7;
      const bf16x8 v = *(const bf16x8*)&ct[row * 72 + seg * 8];
      *(bf16x8*)&Cb[(blockM + wm * (BM / 2) + row) * (long)N + blockN + wn * 64 + seg * 8] = v;
    }
  } else {
    float* ct = (float*)ldsb + wave * (BM / 2) * 68;
#pragma unroll
    for (int j = 0; j < 4; ++j) {
      const float bv = bias[blockN + wn * 64 + j * 16 + l16];
#pragma unroll
      for (int i = 0; i < MI; ++i)
#pragma unroll
        for (int r = 0; r < 4; ++r)
          ct[(i * 16 + q4 * 4 + r) * 68 + j * 16 + l16] = acc[i][j][r] + bv;
    }
    __syncthreads();
    float* Cb = (float*)Cv;
#pragma unroll
    for (int st = 0; st < BM / 8; ++st) {
      const int flat = st * 64 + lane;
      const int row = flat >> 4, seg = flat & 15;
      const f32x4 v = *(const f32x4*)&ct[row * 68 + seg * 4];
      *(f32x4*)&Cb[(blockM + wm * (BM / 2) + row) * (long)N + blockN + wn * 64 + seg * 4] = v;
    }
  }
}

// ---------------------------------------------------------------------------
// Flash-style causal attention, S^T formulation, 32x32x16 MFMA, SPLIT-K.
// Strip = 128 q rows (4 waves x 32 q), tile = 128 keys. Strips qb>=8 split
// into 2 key-chunks (max 8 tiles/block); chunk blocks emit unnormalized
// O(fp32)+m+l, merged by attn_merge. 768 blocks; slot table makes blocks
// {i, i+256, i+512} (same CU under round-robin dispatch) sum to 17 tiles.
// ---------------------------------------------------------------------------
__global__ __launch_bounds__(256, 3) void attn_part(
    const uint16_t* __restrict__ kqv, uint16_t* __restrict__ attn,
    float* __restrict__ pO, float* __restrict__ pml) {
  constexpr int T = 2048, C = 1024, C3 = 3072;
  __shared__ uint16_t KP[128 * 72];   // Kt [key][d] pitch 72
  __shared__ uint16_t Vt[64 * 136];   // V^T [d][key'] pitch 136, key' = (key+16*(d>>3))&127
  uint32_t* VtW = (uint32_t*)Vt;      // pitch 68 dwords

  const int tid = threadIdx.x;
  const int wave = tid >> 6, lane = tid & 63;
  const int l32 = lane & 31, hh = lane >> 5;
  const int g = blockIdx.x >> 8;       // 0..2
  const int rs = blockIdx.x & 255;
  const int s = rs & 7, bh = rs >> 3;
  const int b = bh >> 4, h = bh & 15;
  const size_t base = (size_t)b * T * C3;
  const int hD = h * 64;

  // slot tables: per (g,s) -> (qb, chunk); chunk 2 = whole strip.
  // column sums over g: tiles(g0)+tiles(g1)+tiles(g2) = 17 for every s.
  static const unsigned char QBT[24] = {15,14, 7,13,13,12, 6,10,
                                        15,14,12,11,11,10, 9, 5,
                                         0, 1, 2, 3, 8, 9, 8, 4};
  static const unsigned char CHT[24] = { 0, 0, 2, 0, 1, 0, 2, 0,
                                         1, 1, 1, 0, 1, 1, 1, 2,
                                         2, 2, 2, 2, 1, 0, 0, 2};
  const int idx = g * 8 + s;
  const int qb = QBT[idx], ch = CHT[idx];
  const int hsp = (qb + 2) >> 1;       // ceil((qb+1)/2)
  const bool sp = (ch != 2);
  const int kt0 = (ch == 1) ? hsp : 0;
  const int kt1 = (ch == 0) ? hsp : qb + 1;

  // loop-invariant staging coords
  const int tr = tid >> 3, kch = tid & 7;
  const float sc = 0.125f * 1.4426950408889634f;  // D^-0.5 * log2(e)

  const int qrow = qb * 128 + wave * 32 + l32;   // this lane's q row

  // Q regs: qf[m] = Q[qrow][m*16 + hh*8 .. +7]  (B-frag: col=l32, k=hh*8+j)
  bf16x8 qf[4];
#pragma unroll
  for (int m = 0; m < 4; ++m)
    qf[m] = *(const bf16x8*)&kqv[base + (size_t)qrow * C3 + C + hD + m * 16 + hh * 8];

  f32x16 o[2] = {};   // O[q=(r&3)+8*(r>>2)+4*hh (local)][d = db*32 + l32]
  float m_i = -1e30f, l_i = 0.f;

  // prefetch tile kt0 into VGPRs
  bf16x8 pk[4], pv0[2], pv1[2];
  {
    const int kA = kt0 * 128;
#pragma unroll
    for (int rr = 0; rr < 4; ++rr)
      pk[rr] = *(const bf16x8*)&kqv[base + (size_t)(kA + rr * 32 + tr) * C3 + hD + kch * 8];
#pragma unroll
    for (int s2 = 0; s2 < 2; ++s2) {
      const size_t gg = base + (size_t)(kA + 2 * (s2 * 32 + tr)) * C3 + 2 * C + hD + kch * 8;
      pv0[s2] = *(const bf16x8*)&kqv[gg];
      pv1[s2] = *(const bf16x8*)&kqv[gg + C3];
    }
  }

  for (int kt = kt0; kt < kt1; ++kt) {
    __syncthreads();   // S1: prior tile's KP/Vt reads done
    // stage K from prefetch regs (b128, LDS addr loop-invariant)
#pragma unroll
    for (int rr = 0; rr < 4; ++rr)
      *(bf16x8*)&KP[(rr * 32 + tr) * 72 + kch * 8] = pk[rr];
    // stage V transposed: v_perm pack key-pairs, rot-16 swizzle
#pragma unroll
    for (int s2 = 0; s2 < 2; ++s2) {
      const int colw = ((s2 * 32 + tr) + 8 * kch) & 63;
      const uint32_t* a0 = (const uint32_t*)&pv0[s2];
      const uint32_t* a1 = (const uint32_t*)&pv1[s2];
#pragma unroll
      for (int i = 0; i < 8; ++i) {
        const uint32_t w = (i & 1)
            ? __builtin_amdgcn_perm(a1[i >> 1], a0[i >> 1], 0x07060302u)
            : __builtin_amdgcn_perm(a1[i >> 1], a0[i >> 1], 0x05040100u);
        VtW[(kch * 8 + i) * 68 + colw] = w;
      }
    }
    __syncthreads();   // S2: staging visible
    // prefetch next tile (loads stay in flight across the compute phase)
    if (kt + 1 < kt1) {
      const int kb2 = (kt + 1) * 128;
#pragma unroll
      for (int rr = 0; rr < 4; ++rr)
        pk[rr] = *(const bf16x8*)&kqv[base + (size_t)(kb2 + rr * 32 + tr) * C3 + hD + kch * 8];
#pragma unroll
      for (int s2 = 0; s2 < 2; ++s2) {
        const size_t gg = base + (size_t)(kb2 + 2 * (s2 * 32 + tr)) * C3 + 2 * C + hD + kch * 8;
        pv0[s2] = *(const bf16x8*)&kqv[gg];
        pv1[s2] = *(const bf16x8*)&kqv[gg + C3];
      }
    }

    // on the diagonal tile, wave w only needs key-blocks kb <= w (rest fully masked)
    const int kbmax = (kt == qb) ? wave : 3;   // wave-uniform

    // S^T = K·Q^T : z[kb] is 32key x 32q; lane holds S^T[key(r,hh)][q=l32]
    f32x16 z[4];
#pragma unroll
    for (int kb = 0; kb < 4; ++kb) {
      if (kb <= kbmax) {
        f32x16 zz = {};
#pragma unroll
        for (int m = 0; m < 4; ++m) {
          const bf16x8 kf = *(const bf16x8*)&KP[(kb * 32 + l32) * 72 + m * 16 + hh * 8];
          zz = __builtin_amdgcn_mfma_f32_32x32x16_bf16(kf, qf[m], zz, 0, 0, 0);
        }
        if (kt == qb && kb == wave) {   // partial mask on the diagonal 32x32 block
#pragma unroll
          for (int r = 0; r < 16; ++r) {
            const int keyl = (r & 3) + 8 * (r >> 2) + 4 * hh;
            if (keyl > l32) zz[r] = -1e30f;
          }
        }
        z[kb] = zz;
      }
    }

    // online softmax: each lane owns one q row; keys split lane vs lane+32
    float mloc = -1e30f;
#pragma unroll
    for (int kb = 0; kb < 4; ++kb)
      if (kb <= kbmax)
#pragma unroll
        for (int r = 0; r < 16; ++r) mloc = fmaxf(mloc, z[kb][r]);
    mloc = fmaxf(mloc, __shfl_xor(mloc, 32, 64));
    const float mnew = fmaxf(m_i, mloc * sc);
    const float alpha = exp2f(m_i - mnew);
    const bool mchg = mnew > m_i;
    m_i = mnew;
    float rs2 = 0.f;
#pragma unroll
    for (int kb = 0; kb < 4; ++kb)
      if (kb <= kbmax)
#pragma unroll
        for (int r = 0; r < 16; ++r) {
          const float pe = exp2f(fmaf(z[kb][r], sc, -mnew));
          z[kb][r] = pe;
          rs2 += pe;
        }
    rs2 += __shfl_xor(rs2, 32, 64);
    l_i = l_i * alpha + rs2;
    if (__any(mchg)) {   // O rescale: alpha indexed by O's q row
#pragma unroll
      for (int r = 0; r < 16; ++r) {
        const float ar = __shfl(alpha, (r & 3) + 8 * (r >> 2) + 4 * hh, 64);
        o[0][r] *= ar;
        o[1][r] *= ar;
      }
    }

    // O += P·V : pack P to bf16 and build A-frags in-register.
#pragma unroll
    for (int kb = 0; kb < 4; ++kb) {
      if (kb <= kbmax) {
        uint32_t x0 = pkbf(z[kb][0], z[kb][1]),   x1 = pkbf(z[kb][2], z[kb][3]);
        uint32_t y0 = pkbf(z[kb][4], z[kb][5]),   y1 = pkbf(z[kb][6], z[kb][7]);
        uint32_t x2 = pkbf(z[kb][8], z[kb][9]),   x3 = pkbf(z[kb][10], z[kb][11]);
        uint32_t y2 = pkbf(z[kb][12], z[kb][13]), y3 = pkbf(z[kb][14], z[kb][15]);
        const uint32_t s0 = hh ? x0 : y0, s1 = hh ? x1 : y1;
        const uint32_t s2 = hh ? x2 : y2, s3 = hh ? x3 : y3;
        const uint32_t t0 = __shfl_xor(s0, 32, 64), t1 = __shfl_xor(s1, 32, 64);
        const uint32_t t2 = __shfl_xor(s2, 32, 64), t3 = __shfl_xor(s3, 32, 64);
#pragma unroll
        for (int cc = 0; cc < 2; ++cc) {
          const int c = 2 * kb + cc;
          union { bf16x8 v; uint32_t w[4]; } pa;
          if (cc == 0) {
            pa.w[0] = hh ? t0 : x0; pa.w[1] = hh ? t1 : x1;   // keys 8hh+0..3
            pa.w[2] = hh ? y0 : t0; pa.w[3] = hh ? y1 : t1;   // keys 8hh+4..7
          } else {
            pa.w[0] = hh ? t2 : x2; pa.w[1] = hh ? t3 : x3;
            pa.w[2] = hh ? y2 : t2; pa.w[3] = hh ? y3 : t3;
          }
#pragma unroll
          for (int db = 0; db < 2; ++db) {
            const int d = db * 32 + l32;
            const int col = (c * 16 + hh * 8 + 16 * (d >> 3)) & 127;
            const bf16x8 vf = *(const bf16x8*)&Vt[d * 136 + col];
            o[db] = __builtin_amdgcn_mfma_f32_32x32x16_bf16(pa.v, vf, o[db], 0, 0, 0);
          }
        }
      }
    }
  }

  // epilogue: O rows live at q=(r&3)+8*(r>>2)+4*hh, cols d=db*32+l32
  if (!sp) {
    const size_t obase = (size_t)b * T * C;
    const float linv = 1.0f / l_i;
#pragma unroll
    for (int r = 0; r < 16; ++r) {
      const int ql = (r & 3) + 8 * (r >> 2) + 4 * hh;
      const float lr = __shfl(linv, ql, 64);
      const int q = qb * 128 + wave * 32 + ql;
      const size_t rowoff = obase + (size_t)q * C + hD;
      attn[rowoff + l32] = f2b(o[0][r] * lr);
      attn[rowoff + 32 + l32] = f2b(o[1][r] * lr);
    }
  } else {
    const int slot = (bh * 8 + (qb - 8)) * 2 + ch;
    float* po = pO + (size_t)slot * 8192;   // [128][64] f32
#pragma unroll
    for (int r = 0; r < 16; ++r) {
      const int ql = (r & 3) + 8 * (r >> 2) + 4 * hh;
      const int row = wave * 32 + ql;
      po[row * 64 + l32] = o[0][r];
      po[row * 64 + 32 + l32] = o[1][r];
    }
    if (hh == 0) {   // lane (l32, hh=0) owns softmax state of q row wave*32+l32
      pml[slot * 256 + wave * 32 + l32] = m_i;
      pml[slot * 256 + 128 + wave * 32 + l32] = l_i;
    }
  }
}

// ---------------------------------------------------------------------------
// merge two key-chunk partials: O = (O0*2^(m0-M) + O1*2^(m1-M)) / (l0*2^.. + l1*2^..)
// 256 pairs (bh, qb-8) x 128 q rows; 32 lanes/row, 2 d per lane.
// ---------------------------------------------------------------------------
__global__ __launch_bounds__(256) void attn_merge(
    const float* __restrict__ pO, const float* __restrict__ pml,
    uint16_t* __restrict__ attn) {
  constexpr int T = 2048, C = 1024;
  const int tid = threadIdx.x;
  const int gid = blockIdx.x * 8 + (tid >> 5);   // global row id, 32768 total
  const int l32 = tid & 31;
  const int pair = gid >> 7, q = gid & 127;
  const int bh = pair >> 3, qb = (pair & 7) + 8;
  const int b = bh >> 4, h = bh & 15;
  const int slot0 = pair * 2, slot1 = slot0 + 1;

  const float m0 = pml[slot0 * 256 + q], l0 = pml[slot0 * 256 + 128 + q];
  const float m1 = pml[slot1 * 256 + q], l1 = pml[slot1 * 256 + 128 + q];
  const float M = fmaxf(m0, m1);
  const float w0 = exp2f(m0 - M), w1 = exp2f(m1 - M);
  const float dn = 1.0f / (l0 * w0 + l1 * w1);

  const float2 a = *(const float2*)(pO + (size_t)slot0 * 8192 + q * 64 + l32 * 2);
  const float2 c = *(const float2*)(pO + (size_t)slot1 * 8192 + q * 64 + l32 * 2);
  const float o0 = (a.x * w0 + c.x * w1) * dn;
  const float o1 = (a.y * w0 + c.y * w1) * dn;

  const size_t off = ((size_t)b * T + qb * 128 + q) * C + h * 64 + l32 * 2;
  *(uint32_t*)&attn[off] = pkbf(o0, o1);
}

extern "C" void kernel_launch(void* const* d_in, const int* in_sizes, int n_in,
                              void* d_out, int out_size, void* d_ws, size_t ws_size,
                              hipStream_t stream) {
  const float* x      = (const float*)d_in[0];  // (2,2048,1024) fp32
  const float* w_attn = (const float*)d_in[1];  // (3072,1024)  fp32
  const float* b_attn = (const float*)d_in[2];  // (3072,)      fp32
  const float* w_proj = (const float*)d_in[3];  // (1024,1024)  fp32
  const float* b_proj = (const float*)d_in[4];  // (1024,)      fp32
  float* out = (float*)d_out;                   // (2,2048,1024) fp32

  // ws layout (bf16): xb | wab | wpb | kqv | attnb
  uint16_t* xb    = (uint16_t*)d_ws;                     // 4096*1024
  uint16_t* wab   = xb  + (size_t)4096 * 1024;           // 3072*1024
  uint16_t* wpb   = wab + (size_t)3072 * 1024;           // 1024*1024
  uint16_t* kqv   = wpb + (size_t)1024 * 1024;           // 4096*3072
  uint16_t* attnb = kqv + (size_t)4096 * 3072;           // 4096*1024

  // split-K partials live in dead windows:
  //   pO  (512 slots x 128x64 f32 = 16.78MB) -> d_out (overwritten by gemm2 at the end)
  //   pml (512 slots x 256 f32 = 0.5MB)      -> xb region (dead after gemm1 reads it)
  float* pO  = (float*)d_out;
  float* pml = (float*)xb;

  dim3 blk(256, 1, 1);
  hipLaunchKernelGGL(cvt_all, dim3(8192), blk, 0, stream, x, w_attn, w_proj, xb, wab, wpb);

  hipLaunchKernelGGL((gemm_bt_bias<128, true>), dim3(3072 / 128, 4096 / 128, 1), blk, 0, stream,
                     xb, wab, b_attn, (void*)kqv, 4096, 3072, 1024);
  hipLaunchKernelGGL(attn_part, dim3(768, 1, 1), blk, 0, stream, kqv, attnb, pO, pml);
  hipLaunchKernelGGL(attn_merge, dim3(4096, 1, 1), blk, 0, stream, pO, pml, attnb);
  hipLaunchKernelGGL((gemm_bt_bias<64, false>), dim3(1024 / 128, 4096 / 64, 1), blk, 0, stream,
                     attnb, wpb, b_proj, (void*)out, 4096, 1024, 1024);
}

// Round 5
// 223.819 us; speedup vs baseline: 1.0582x; 1.0582x over previous
//
#include <hip/hip_runtime.h>
#include <hip/hip_bf16.h>
#include <cstdint>

// bf16 fragments as 8 x short (4 VGPRs) per cdna_hip_programming.md §3
typedef __attribute__((ext_vector_type(8))) short bf16x8;
typedef __attribute__((ext_vector_type(4))) float f32x4;
typedef __attribute__((ext_vector_type(16))) float f32x16;
typedef __attribute__((ext_vector_type(4))) uint16_t u16x4;

__device__ __forceinline__ uint16_t f2b(float f) {
  union { float f; uint32_t i; } v; v.f = f;
  return (uint16_t)((v.i + 0x7FFFu + ((v.i >> 16) & 1u)) >> 16);  // RNE
}

__device__ __forceinline__ uint32_t pkbf(float a, float b) {
  union { __hip_bfloat162 h2; uint32_t u; } c;
  c.h2 = __float22bfloat162_rn(make_float2(a, b));
  return c.u;   // low16 = a, high16 = b
}

// async global->LDS, 16B per lane; LDS dest is wave-uniform base + lane*16
#define GLDS16(g, l) __builtin_amdgcn_global_load_lds( \
    (const __attribute__((address_space(1))) void*)(g), \
    (__attribute__((address_space(3))) void*)(l), 16, 0, 0)

// ---------------------------------------------------------------------------
// fp32 -> bf16 convert (RNE) for all three inputs in one launch
// ---------------------------------------------------------------------------
__global__ __launch_bounds__(256) void cvt_all(
    const float* __restrict__ x, const float* __restrict__ wa, const float* __restrict__ wp,
    uint16_t* __restrict__ xb, uint16_t* __restrict__ wab, uint16_t* __restrict__ wpb) {
  const int i = (blockIdx.x * 256 + threadIdx.x) * 4;
  const float* src; uint16_t* dst; int off;
  if (i < 4194304)      { src = x;  dst = xb;  off = i; }
  else if (i < 7340032) { src = wa; dst = wab; off = i - 4194304; }
  else                  { src = wp; dst = wpb; off = i - 7340032; }
  const float4 v = *(const float4*)(src + off);
  u16x4 o;
  o.x = f2b(v.x); o.y = f2b(v.y); o.z = f2b(v.z); o.w = f2b(v.w);
  *(u16x4*)(dst + off) = o;
}

// ---------------------------------------------------------------------------
// C[M,N] = A[M,K] @ B[N,K]^T + bias[N]. A,B bf16, bias fp32, fp32 accumulate.
// ---------------------------------------------------------------------------
template <int BM, bool OUT_BF16>
__global__ __launch_bounds__(256) void gemm_bt_bias(
    const uint16_t* __restrict__ A, const uint16_t* __restrict__ B,
    const float* __restrict__ bias, void* __restrict__ Cv,
    int M, int N, int K) {
  constexpr int MI = BM / 32;            // acc rows of 16
  constexpr int CA = BM / 16;            // A chunks per k-half
  constexpr int CPW = (2 * (CA + 8)) / 4;
  constexpr int CT_PITCH = OUT_BF16 ? 72 : 68;
  constexpr size_t CT_BYTES = (size_t)4 * (BM / 2) * CT_PITCH * (OUT_BF16 ? 2 : 4);
  constexpr size_t ST_BYTES = (size_t)(2 * (BM * 32 + 4096)) * 2;
  constexpr size_t LB = CT_BYTES > ST_BYTES ? CT_BYTES : ST_BYTES;
  __shared__ alignas(16) unsigned char ldsb[LB];
  uint16_t* lds = (uint16_t*)ldsb;
  const int offB0 = BM * 32;             // u16 offsets
  const int offA1 = BM * 32 + 4096;
  const int offB1 = 2 * BM * 32 + 4096;

  const int tid = threadIdx.x;
  const int wave = tid >> 6, lane = tid & 63;
  const int q4 = lane >> 4, l16 = lane & 15;
  const int wm = wave >> 1, wn = wave & 1;
  const long blockM = (long)blockIdx.y * BM;
  const long blockN = (long)blockIdx.x * 128;

  f32x4 acc[MI][4] = {};

  for (int k0 = 0; k0 < K; k0 += 64) {
#pragma unroll
    for (int c = 0; c < CPW; ++c) {
      const int id = c * 4 + wave;       // wave-uniform
      const uint16_t* mat; long rowBase; int a, kk, off;
      if (id < CA)               { mat = A; rowBase = blockM; a = id;            kk = k0;      off = 0; }
      else if (id < CA + 8)      { mat = B; rowBase = blockN; a = id - CA;       kk = k0;      off = offB0; }
      else if (id < 2 * CA + 8)  { mat = A; rowBase = blockM; a = id - CA - 8;   kk = k0 + 32; off = offA1; }
      else                       { mat = B; rowBase = blockN; a = id - 2*CA - 8; kk = k0 + 32; off = offB1; }
      const int flat = a * 64 + lane;
      const int row = flat >> 2, seg = flat & 3;
      GLDS16(mat + (rowBase + row) * (long)K + kk + seg * 8, lds + off + a * 512);
    }
    __syncthreads();
#pragma unroll
    for (int h = 0; h < 2; ++h) {
      const uint16_t* Ah = lds + (h ? offA1 : 0);
      const uint16_t* Bh = lds + (h ? offB1 : offB0);
      bf16x8 af[MI], bfr[4];
#pragma unroll
      for (int i = 0; i < MI; ++i)
        af[i] = *(const bf16x8*)&Ah[(wm * (BM / 2) + i * 16 + l16) * 32 + q4 * 8];
#pragma unroll
      for (int j = 0; j < 4; ++j)
        bfr[j] = *(const bf16x8*)&Bh[(wn * 64 + j * 16 + l16) * 32 + q4 * 8];
#pragma unroll
      for (int i = 0; i < MI; ++i)
#pragma unroll
        for (int j = 0; j < 4; ++j)
          acc[i][j] = __builtin_amdgcn_mfma_f32_16x16x32_bf16(af[i], bfr[j], acc[i][j], 0, 0, 0);
    }
    __syncthreads();
  }

  // epilogue: acc (C/D layout: col=l16, row=q4*4+r) -> per-wave LDS tile -> vector stores
  if (OUT_BF16) {
    uint16_t* ct = lds + wave * (BM / 2) * 72;
#pragma unroll
    for (int j = 0; j < 4; ++j) {
      const float bv = bias[blockN + wn * 64 + j * 16 + l16];
#pragma unroll
      for (int i = 0; i < MI; ++i)
#pragma unroll
        for (int r = 0; r < 4; ++r)
          ct[(i * 16 + q4 * 4 + r) * 72 + j * 16 + l16] = f2b(acc[i][j][r] + bv);
    }
    __syncthreads();
    uint16_t* Cb = (uint16_t*)Cv;
#pragma unroll
    for (int st = 0; st < BM / 16; ++st) {
      const int flat = st * 64 + lane;
      const int row = flat >> 3, seg = flat & 7;
      const bf16x8 v = *(const bf16x8*)&ct[row * 72 + seg * 8];
      *(bf16x8*)&Cb[(blockM + wm * (BM / 2) + row) * (long)N + blockN + wn * 64 + seg * 8] = v;
    }
  } else {
    float* ct = (float*)ldsb + wave * (BM / 2) * 68;
#pragma unroll
    for (int j = 0; j < 4; ++j) {
      const float bv = bias[blockN + wn * 64 + j * 16 + l16];
#pragma unroll
      for (int i = 0; i < MI; ++i)
#pragma unroll
        for (int r = 0; r < 4; ++r)
          ct[(i * 16 + q4 * 4 + r) * 68 + j * 16 + l16] = acc[i][j][r] + bv;
    }
    __syncthreads();
    float* Cb = (float*)Cv;
#pragma unroll
    for (int st = 0; st < BM / 8; ++st) {
      const int flat = st * 64 + lane;
      const int row = flat >> 4, seg = flat & 15;
      const f32x4 v = *(const f32x4*)&ct[row * 68 + seg * 4];
      *(f32x4*)&Cb[(blockM + wm * (BM / 2) + row) * (long)N + blockN + wn * 64 + seg * 4] = v;
    }
  }
}

// ---------------------------------------------------------------------------
// Flash-style causal attention, S^T formulation, 32x32x16 MFMA, SPLIT-K.
// Strip = 128 q rows (4 waves x 32 q), tile = 128 keys. Strips qb>=8 split
// into 2 key-chunks (max 8 tiles/block); chunk blocks emit unnormalized
// O(fp32)+m+l, merged by attn_merge. 768 blocks.
// blockIdx = t*32 + bh:  bh in LOW bits so XCD (=blockIdx%8) serves only 4
// of 32 heads -> per-XCD K/V working set 2MB, fits private L2 (round-4
// lesson: s-in-low-bits thrashed L2, FETCH 12->107MB). Blocks {i,i+256,
// i+512} share a CU (XCD=i%8, CU=(i>>3)%32) and their t-columns {t,t+8,
// t+16} sum to exactly 17 tiles (tables verified).
// ---------------------------------------------------------------------------
__global__ __launch_bounds__(256, 3) void attn_part(
    const uint16_t* __restrict__ kqv, uint16_t* __restrict__ attn,
    float* __restrict__ pO, float* __restrict__ pml) {
  constexpr int T = 2048, C = 1024, C3 = 3072;
  __shared__ uint16_t KP[128 * 72];   // Kt [key][d] pitch 72
  __shared__ uint16_t Vt[64 * 136];   // V^T [d][key'] pitch 136, key' = (key+16*(d>>3))&127
  uint32_t* VtW = (uint32_t*)Vt;      // pitch 68 dwords

  const int tid = threadIdx.x;
  const int wave = tid >> 6, lane = tid & 63;
  const int l32 = lane & 31, hh = lane >> 5;
  const int bh = blockIdx.x & 31;      // LOW bits: head locality per XCD
  const int t = blockIdx.x >> 5;       // 0..23 slot column
  const int b = bh >> 4, h = bh & 15;
  const size_t base = (size_t)b * T * C3;
  const int hD = h * 64;

  // slot tables: per t -> (qb, chunk); chunk 2 = whole strip.
  // column sums over {t, t+8, t+16} = 17 tiles for every t in 0..7.
  static const unsigned char QBT[24] = {15,14, 7,13,13,12, 6,10,
                                        15,14,12,11,11,10, 9, 5,
                                         0, 1, 2, 3, 8, 9, 8, 4};
  static const unsigned char CHT[24] = { 0, 0, 2, 0, 1, 0, 2, 0,
                                         1, 1, 1, 0, 1, 1, 1, 2,
                                         2, 2, 2, 2, 1, 0, 0, 2};
  const int qb = QBT[t], ch = CHT[t];
  const int hsp = (qb + 2) >> 1;       // ceil((qb+1)/2)
  const bool sp = (ch != 2);
  const int kt0 = (ch == 1) ? hsp : 0;
  const int kt1 = (ch == 0) ? hsp : qb + 1;

  // loop-invariant staging coords
  const int tr = tid >> 3, kch = tid & 7;
  const float sc = 0.125f * 1.4426950408889634f;  // D^-0.5 * log2(e)

  const int qrow = qb * 128 + wave * 32 + l32;   // this lane's q row

  // Q regs: qf[m] = Q[qrow][m*16 + hh*8 .. +7]  (B-frag: col=l32, k=hh*8+j)
  bf16x8 qf[4];
#pragma unroll
  for (int m = 0; m < 4; ++m)
    qf[m] = *(const bf16x8*)&kqv[base + (size_t)qrow * C3 + C + hD + m * 16 + hh * 8];

  f32x16 o[2] = {};   // O[q=(r&3)+8*(r>>2)+4*hh (local)][d = db*32 + l32]
  float m_i = -1e30f, l_i = 0.f;

  // prefetch tile kt0 into VGPRs
  bf16x8 pk[4], pv0[2], pv1[2];
  {
    const int kA = kt0 * 128;
#pragma unroll
    for (int rr = 0; rr < 4; ++rr)
      pk[rr] = *(const bf16x8*)&kqv[base + (size_t)(kA + rr * 32 + tr) * C3 + hD + kch * 8];
#pragma unroll
    for (int s2 = 0; s2 < 2; ++s2) {
      const size_t gg = base + (size_t)(kA + 2 * (s2 * 32 + tr)) * C3 + 2 * C + hD + kch * 8;
      pv0[s2] = *(const bf16x8*)&kqv[gg];
      pv1[s2] = *(const bf16x8*)&kqv[gg + C3];
    }
  }

  for (int kt = kt0; kt < kt1; ++kt) {
    __syncthreads();   // S1: prior tile's KP/Vt reads done
    // stage K from prefetch regs (b128, LDS addr loop-invariant)
#pragma unroll
    for (int rr = 0; rr < 4; ++rr)
      *(bf16x8*)&KP[(rr * 32 + tr) * 72 + kch * 8] = pk[rr];
    // stage V transposed: v_perm pack key-pairs, rot-16 swizzle
#pragma unroll
    for (int s2 = 0; s2 < 2; ++s2) {
      const int colw = ((s2 * 32 + tr) + 8 * kch) & 63;
      const uint32_t* a0 = (const uint32_t*)&pv0[s2];
      const uint32_t* a1 = (const uint32_t*)&pv1[s2];
#pragma unroll
      for (int i = 0; i < 8; ++i) {
        const uint32_t w = (i & 1)
            ? __builtin_amdgcn_perm(a1[i >> 1], a0[i >> 1], 0x07060302u)
            : __builtin_amdgcn_perm(a1[i >> 1], a0[i >> 1], 0x05040100u);
        VtW[(kch * 8 + i) * 68 + colw] = w;
      }
    }
    __syncthreads();   // S2: staging visible
    // prefetch next tile (loads stay in flight across the compute phase)
    if (kt + 1 < kt1) {
      const int kb2 = (kt + 1) * 128;
#pragma unroll
      for (int rr = 0; rr < 4; ++rr)
        pk[rr] = *(const bf16x8*)&kqv[base + (size_t)(kb2 + rr * 32 + tr) * C3 + hD + kch * 8];
#pragma unroll
      for (int s2 = 0; s2 < 2; ++s2) {
        const size_t gg = base + (size_t)(kb2 + 2 * (s2 * 32 + tr)) * C3 + 2 * C + hD + kch * 8;
        pv0[s2] = *(const bf16x8*)&kqv[gg];
        pv1[s2] = *(const bf16x8*)&kqv[gg + C3];
      }
    }

    // on the diagonal tile, wave w only needs key-blocks kb <= w (rest fully masked)
    const int kbmax = (kt == qb) ? wave : 3;   // wave-uniform

    // S^T = K·Q^T : z[kb] is 32key x 32q; lane holds S^T[key(r,hh)][q=l32]
    f32x16 z[4];
#pragma unroll
    for (int kb = 0; kb < 4; ++kb) {
      if (kb <= kbmax) {
        f32x16 zz = {};
#pragma unroll
        for (int m = 0; m < 4; ++m) {
          const bf16x8 kf = *(const bf16x8*)&KP[(kb * 32 + l32) * 72 + m * 16 + hh * 8];
          zz = __builtin_amdgcn_mfma_f32_32x32x16_bf16(kf, qf[m], zz, 0, 0, 0);
        }
        if (kt == qb && kb == wave) {   // partial mask on the diagonal 32x32 block
#pragma unroll
          for (int r = 0; r < 16; ++r) {
            const int keyl = (r & 3) + 8 * (r >> 2) + 4 * hh;
            if (keyl > l32) zz[r] = -1e30f;
          }
        }
        z[kb] = zz;
      }
    }

    // online softmax: each lane owns one q row; keys split lane vs lane+32
    float mloc = -1e30f;
#pragma unroll
    for (int kb = 0; kb < 4; ++kb)
      if (kb <= kbmax)
#pragma unroll
        for (int r = 0; r < 16; ++r) mloc = fmaxf(mloc, z[kb][r]);
    mloc = fmaxf(mloc, __shfl_xor(mloc, 32, 64));
    const float mnew = fmaxf(m_i, mloc * sc);
    const float alpha = exp2f(m_i - mnew);
    const bool mchg = mnew > m_i;
    m_i = mnew;
    float rs2 = 0.f;
#pragma unroll
    for (int kb = 0; kb < 4; ++kb)
      if (kb <= kbmax)
#pragma unroll
        for (int r = 0; r < 16; ++r) {
          const float pe = exp2f(fmaf(z[kb][r], sc, -mnew));
          z[kb][r] = pe;
          rs2 += pe;
        }
    rs2 += __shfl_xor(rs2, 32, 64);
    l_i = l_i * alpha + rs2;
    if (__any(mchg)) {   // O rescale: alpha indexed by O's q row
#pragma unroll
      for (int r = 0; r < 16; ++r) {
        const float ar = __shfl(alpha, (r & 3) + 8 * (r >> 2) + 4 * hh, 64);
        o[0][r] *= ar;
        o[1][r] *= ar;
      }
    }

    // O += P·V : pack P to bf16 and build A-frags in-register.
#pragma unroll
    for (int kb = 0; kb < 4; ++kb) {
      if (kb <= kbmax) {
        uint32_t x0 = pkbf(z[kb][0], z[kb][1]),   x1 = pkbf(z[kb][2], z[kb][3]);
        uint32_t y0 = pkbf(z[kb][4], z[kb][5]),   y1 = pkbf(z[kb][6], z[kb][7]);
        uint32_t x2 = pkbf(z[kb][8], z[kb][9]),   x3 = pkbf(z[kb][10], z[kb][11]);
        uint32_t y2 = pkbf(z[kb][12], z[kb][13]), y3 = pkbf(z[kb][14], z[kb][15]);
        const uint32_t s0 = hh ? x0 : y0, s1 = hh ? x1 : y1;
        const uint32_t s2 = hh ? x2 : y2, s3 = hh ? x3 : y3;
        const uint32_t t0 = __shfl_xor(s0, 32, 64), t1 = __shfl_xor(s1, 32, 64);
        const uint32_t t2 = __shfl_xor(s2, 32, 64), t3 = __shfl_xor(s3, 32, 64);
#pragma unroll
        for (int cc = 0; cc < 2; ++cc) {
          const int c = 2 * kb + cc;
          union { bf16x8 v; uint32_t w[4]; } pa;
          if (cc == 0) {
            pa.w[0] = hh ? t0 : x0; pa.w[1] = hh ? t1 : x1;   // keys 8hh+0..3
            pa.w[2] = hh ? y0 : t0; pa.w[3] = hh ? y1 : t1;   // keys 8hh+4..7
          } else {
            pa.w[0] = hh ? t2 : x2; pa.w[1] = hh ? t3 : x3;
            pa.w[2] = hh ? y2 : t2; pa.w[3] = hh ? y3 : t3;
          }
#pragma unroll
          for (int db = 0; db < 2; ++db) {
            const int d = db * 32 + l32;
            const int col = (c * 16 + hh * 8 + 16 * (d >> 3)) & 127;
            const bf16x8 vf = *(const bf16x8*)&Vt[d * 136 + col];
            o[db] = __builtin_amdgcn_mfma_f32_32x32x16_bf16(pa.v, vf, o[db], 0, 0, 0);
          }
        }
      }
    }
  }

  // epilogue: O rows live at q=(r&3)+8*(r>>2)+4*hh, cols d=db*32+l32
  if (!sp) {
    const size_t obase = (size_t)b * T * C;
    const float linv = 1.0f / l_i;
#pragma unroll
    for (int r = 0; r < 16; ++r) {
      const int ql = (r & 3) + 8 * (r >> 2) + 4 * hh;
      const float lr = __shfl(linv, ql, 64);
      const int q = qb * 128 + wave * 32 + ql;
      const size_t rowoff = obase + (size_t)q * C + hD;
      attn[rowoff + l32] = f2b(o[0][r] * lr);
      attn[rowoff + 32 + l32] = f2b(o[1][r] * lr);
    }
  } else {
    const int slot = (bh * 8 + (qb - 8)) * 2 + ch;
    float* po = pO + (size_t)slot * 8192;   // [128][64] f32
#pragma unroll
    for (int r = 0; r < 16; ++r) {
      const int ql = (r & 3) + 8 * (r >> 2) + 4 * hh;
      const int row = wave * 32 + ql;
      po[row * 64 + l32] = o[0][r];
      po[row * 64 + 32 + l32] = o[1][r];
    }
    if (hh == 0) {   // lane (l32, hh=0) owns softmax state of q row wave*32+l32
      pml[slot * 256 + wave * 32 + l32] = m_i;
      pml[slot * 256 + 128 + wave * 32 + l32] = l_i;
    }
  }
}

// ---------------------------------------------------------------------------
// merge two key-chunk partials: O = (O0*2^(m0-M) + O1*2^(m1-M)) / (l0*2^.. + l1*2^..)
// 256 pairs (bh, qb-8) x 128 q rows; 32 lanes/row, 2 d per lane.
// ---------------------------------------------------------------------------
__global__ __launch_bounds__(256) void attn_merge(
    const float* __restrict__ pO, const float* __restrict__ pml,
    uint16_t* __restrict__ attn) {
  constexpr int T = 2048, C = 1024;
  const int tid = threadIdx.x;
  const int gid = blockIdx.x * 8 + (tid >> 5);   // global row id, 32768 total
  const int l32 = tid & 31;
  const int pair = gid >> 7, q = gid & 127;
  const int bh = pair >> 3, qb = (pair & 7) + 8;
  const int b = bh >> 4, h = bh & 15;
  const int slot0 = pair * 2, slot1 = slot0 + 1;

  const float m0 = pml[slot0 * 256 + q], l0 = pml[slot0 * 256 + 128 + q];
  const float m1 = pml[slot1 * 256 + q], l1 = pml[slot1 * 256 + 128 + q];
  const float M = fmaxf(m0, m1);
  const float w0 = exp2f(m0 - M), w1 = exp2f(m1 - M);
  const float dn = 1.0f / (l0 * w0 + l1 * w1);

  const float2 a = *(const float2*)(pO + (size_t)slot0 * 8192 + q * 64 + l32 * 2);
  const float2 c = *(const float2*)(pO + (size_t)slot1 * 8192 + q * 64 + l32 * 2);
  const float o0 = (a.x * w0 + c.x * w1) * dn;
  const float o1 = (a.y * w0 + c.y * w1) * dn;

  const size_t off = ((size_t)b * T + qb * 128 + q) * C + h * 64 + l32 * 2;
  *(uint32_t*)&attn[off] = pkbf(o0, o1);
}

extern "C" void kernel_launch(void* const* d_in, const int* in_sizes, int n_in,
                              void* d_out, int out_size, void* d_ws, size_t ws_size,
                              hipStream_t stream) {
  const float* x      = (const float*)d_in[0];  // (2,2048,1024) fp32
  const float* w_attn = (const float*)d_in[1];  // (3072,1024)  fp32
  const float* b_attn = (const float*)d_in[2];  // (3072,)      fp32
  const float* w_proj = (const float*)d_in[3];  // (1024,1024)  fp32
  const float* b_proj = (const float*)d_in[4];  // (1024,)      fp32
  float* out = (float*)d_out;                   // (2,2048,1024) fp32

  // ws layout (bf16): xb | wab | wpb | kqv | attnb
  uint16_t* xb    = (uint16_t*)d_ws;                     // 4096*1024
  uint16_t* wab   = xb  + (size_t)4096 * 1024;           // 3072*1024
  uint16_t* wpb   = wab + (size_t)3072 * 1024;           // 1024*1024
  uint16_t* kqv   = wpb + (size_t)1024 * 1024;           // 4096*3072
  uint16_t* attnb = kqv + (size_t)4096 * 3072;           // 4096*1024

  // split-K partials live in dead windows:
  //   pO  (512 slots x 128x64 f32 = 16.78MB) -> d_out (overwritten by gemm2 at the end)
  //   pml (512 slots x 256 f32 = 0.5MB)      -> xb region (dead after gemm1 reads it)
  float* pO  = (float*)d_out;
  float* pml = (float*)xb;

  dim3 blk(256, 1, 1);
  hipLaunchKernelGGL(cvt_all, dim3(8192), blk, 0, stream, x, w_attn, w_proj, xb, wab, wpb);

  hipLaunchKernelGGL((gemm_bt_bias<128, true>), dim3(3072 / 128, 4096 / 128, 1), blk, 0, stream,
                     xb, wab, b_attn, (void*)kqv, 4096, 3072, 1024);
  hipLaunchKernelGGL(attn_part, dim3(768, 1, 1), blk, 0, stream, kqv, attnb, pO, pml);
  hipLaunchKernelGGL(attn_merge, dim3(4096, 1, 1), blk, 0, stream, pO, pml, attnb);
  hipLaunchKernelGGL((gemm_bt_bias<64, false>), dim3(1024 / 128, 4096 / 64, 1), blk, 0, stream,
                     attnb, wpb, b_proj, (void*)out, 4096, 1024, 1024);
}

// Round 7
// 191.208 us; speedup vs baseline: 1.2387x; 1.1706x over previous
//
#include <hip/hip_runtime.h>
#include <hip/hip_bf16.h>
#include <cstdint>

// bf16 fragments as 8 x short (4 VGPRs) per cdna_hip_programming.md §3
typedef __attribute__((ext_vector_type(8))) short bf16x8;
typedef __attribute__((ext_vector_type(4))) float f32x4;
typedef __attribute__((ext_vector_type(16))) float f32x16;
typedef __attribute__((ext_vector_type(4))) uint16_t u16x4;

__device__ __forceinline__ uint16_t f2b(float f) {
  union { float f; uint32_t i; } v; v.f = f;
  return (uint16_t)((v.i + 0x7FFFu + ((v.i >> 16) & 1u)) >> 16);  // RNE
}

__device__ __forceinline__ uint32_t pkbf(float a, float b) {
  union { __hip_bfloat162 h2; uint32_t u; } c;
  c.h2 = __float22bfloat162_rn(make_float2(a, b));
  return c.u;   // low16 = a, high16 = b
}

// async global->LDS, 16B per lane; LDS dest is wave-uniform base + lane*16
#define GLDS16(g, l) __builtin_amdgcn_global_load_lds( \
    (const __attribute__((address_space(1))) void*)(g), \
    (__attribute__((address_space(3))) void*)(l), 16, 0, 0)

// ---------------------------------------------------------------------------
// fp32 -> bf16 convert (RNE) for all three inputs in one launch
// ---------------------------------------------------------------------------
__global__ __launch_bounds__(256) void cvt_all(
    const float* __restrict__ x, const float* __restrict__ wa, const float* __restrict__ wp,
    uint16_t* __restrict__ xb, uint16_t* __restrict__ wab, uint16_t* __restrict__ wpb) {
  const int i = (blockIdx.x * 256 + threadIdx.x) * 4;
  const float* src; uint16_t* dst; int off;
  if (i < 4194304)      { src = x;  dst = xb;  off = i; }
  else if (i < 7340032) { src = wa; dst = wab; off = i - 4194304; }
  else                  { src = wp; dst = wpb; off = i - 7340032; }
  const float4 v = *(const float4*)(src + off);
  u16x4 o;
  o.x = f2b(v.x); o.y = f2b(v.y); o.z = f2b(v.z); o.w = f2b(v.w);
  *(u16x4*)(dst + off) = o;
}

// ---------------------------------------------------------------------------
// C[M,N] = A[M,K] @ B[N,K]^T + bias[N]. A,B bf16, bias fp32, fp32 accumulate.
// ---------------------------------------------------------------------------
template <int BM, bool OUT_BF16>
__global__ __launch_bounds__(256) void gemm_bt_bias(
    const uint16_t* __restrict__ A, const uint16_t* __restrict__ B,
    const float* __restrict__ bias, void* __restrict__ Cv,
    int M, int N, int K) {
  constexpr int MI = BM / 32;            // acc rows of 16
  constexpr int CA = BM / 16;            // A chunks per k-half
  constexpr int CPW = (2 * (CA + 8)) / 4;
  constexpr int CT_PITCH = OUT_BF16 ? 72 : 68;
  constexpr size_t CT_BYTES = (size_t)4 * (BM / 2) * CT_PITCH * (OUT_BF16 ? 2 : 4);
  constexpr size_t ST_BYTES = (size_t)(2 * (BM * 32 + 4096)) * 2;
  constexpr size_t LB = CT_BYTES > ST_BYTES ? CT_BYTES : ST_BYTES;
  __shared__ alignas(16) unsigned char ldsb[LB];
  uint16_t* lds = (uint16_t*)ldsb;
  const int offB0 = BM * 32;             // u16 offsets
  const int offA1 = BM * 32 + 4096;
  const int offB1 = 2 * BM * 32 + 4096;

  const int tid = threadIdx.x;
  const int wave = tid >> 6, lane = tid & 63;
  const int q4 = lane >> 4, l16 = lane & 15;
  const int wm = wave >> 1, wn = wave & 1;
  const long blockM = (long)blockIdx.y * BM;
  const long blockN = (long)blockIdx.x * 128;

  f32x4 acc[MI][4] = {};

  for (int k0 = 0; k0 < K; k0 += 64) {
#pragma unroll
    for (int c = 0; c < CPW; ++c) {
      const int id = c * 4 + wave;       // wave-uniform
      const uint16_t* mat; long rowBase; int a, kk, off;
      if (id < CA)               { mat = A; rowBase = blockM; a = id;            kk = k0;      off = 0; }
      else if (id < CA + 8)      { mat = B; rowBase = blockN; a = id - CA;       kk = k0;      off = offB0; }
      else if (id < 2 * CA + 8)  { mat = A; rowBase = blockM; a = id - CA - 8;   kk = k0 + 32; off = offA1; }
      else                       { mat = B; rowBase = blockN; a = id - 2*CA - 8; kk = k0 + 32; off = offB1; }
      const int flat = a * 64 + lane;
      const int row = flat >> 2, seg = flat & 3;
      GLDS16(mat + (rowBase + row) * (long)K + kk + seg * 8, lds + off + a * 512);
    }
    __syncthreads();
#pragma unroll
    for (int h = 0; h < 2; ++h) {
      const uint16_t* Ah = lds + (h ? offA1 : 0);
      const uint16_t* Bh = lds + (h ? offB1 : offB0);
      bf16x8 af[MI], bfr[4];
#pragma unroll
      for (int i = 0; i < MI; ++i)
        af[i] = *(const bf16x8*)&Ah[(wm * (BM / 2) + i * 16 + l16) * 32 + q4 * 8];
#pragma unroll
      for (int j = 0; j < 4; ++j)
        bfr[j] = *(const bf16x8*)&Bh[(wn * 64 + j * 16 + l16) * 32 + q4 * 8];
#pragma unroll
      for (int i = 0; i < MI; ++i)
#pragma unroll
        for (int j = 0; j < 4; ++j)
          acc[i][j] = __builtin_amdgcn_mfma_f32_16x16x32_bf16(af[i], bfr[j], acc[i][j], 0, 0, 0);
    }
    __syncthreads();
  }

  // epilogue: acc (C/D layout: col=l16, row=q4*4+r) -> per-wave LDS tile -> vector stores
  if (OUT_BF16) {
    uint16_t* ct = lds + wave * (BM / 2) * 72;
#pragma unroll
    for (int j = 0; j < 4; ++j) {
      const float bv = bias[blockN + wn * 64 + j * 16 + l16];
#pragma unroll
      for (int i = 0; i < MI; ++i)
#pragma unroll
        for (int r = 0; r < 4; ++r)
          ct[(i * 16 + q4 * 4 + r) * 72 + j * 16 + l16] = f2b(acc[i][j][r] + bv);
    }
    __syncthreads();
    uint16_t* Cb = (uint16_t*)Cv;
#pragma unroll
    for (int st = 0; st < BM / 16; ++st) {
      const int flat = st * 64 + lane;
      const int row = flat >> 3, seg = flat & 7;
      const bf16x8 v = *(const bf16x8*)&ct[row * 72 + seg * 8];
      *(bf16x8*)&Cb[(blockM + wm * (BM / 2) + row) * (long)N + blockN + wn * 64 + seg * 8] = v;
    }
  } else {
    float* ct = (float*)ldsb + wave * (BM / 2) * 68;
#pragma unroll
    for (int j = 0; j < 4; ++j) {
      const float bv = bias[blockN + wn * 64 + j * 16 + l16];
#pragma unroll
      for (int i = 0; i < MI; ++i)
#pragma unroll
        for (int r = 0; r < 4; ++r)
          ct[(i * 16 + q4 * 4 + r) * 68 + j * 16 + l16] = acc[i][j][r] + bv;
    }
    __syncthreads();
    float* Cb = (float*)Cv;
#pragma unroll
    for (int st = 0; st < BM / 8; ++st) {
      const int flat = st * 64 + lane;
      const int row = flat >> 4, seg = flat & 15;
      const f32x4 v = *(const f32x4*)&ct[row * 68 + seg * 4];
      *(f32x4*)&Cb[(blockM + wm * (BM / 2) + row) * (long)N + blockN + wn * 64 + seg * 4] = v;
    }
  }
}

// ---------------------------------------------------------------------------
// Flash-style causal attention, S^T formulation, 32x32x16 MFMA,
// IN-BLOCK split-K: block = 64 q rows; each of 4 waves handles keys
// w*32..w*32+31 of every 128-key tile across ALL 64 q (per-wave online
// softmax over its key subset), merged once per strip via LDS.
// Per-wave LDS reads: 4 kf + 4 vf b128 per tile (K/V read ONCE per tile).
// Grid: 1024 blocks = round-1's proven schedule (64-row strips, qb=31-sidx
// big-first backfill, bh in LOW bits for XCD L2 locality).
// NaN guard: pm floored at -3e4. Without it, an all-masked first tile sets
// m_i to the ROUNDED -1e30*sc, and exp2f(fmaf(z,sc,-m_i)) sees only the
// fmaf rounding residual (~±1e22) -> exp2(+huge) = inf -> NaN in merge.
// ---------------------------------------------------------------------------
__global__ __launch_bounds__(256, 2) void attn_flash(
    const uint16_t* __restrict__ kqv, uint16_t* __restrict__ attn) {
  constexpr int T = 2048, C = 1024, C3 = 3072;
  __shared__ alignas(16) unsigned char ldsb[35840];
  uint16_t* KP = (uint16_t*)ldsb;             // [128][72] u16 (tile phase)
  uint16_t* Vt = (uint16_t*)(ldsb + 18432);   // [64][136] u16, rot-16 swizzle
  uint32_t* VtW = (uint32_t*)(ldsb + 18432);  // pitch 68 dwords
  float* mlb  = (float*)ldsb;                 // [4][2][32] (merge overlay)
  float* obuf = (float*)(ldsb + 1024);        // [4][32][66] f32 (merge overlay)

  const int tid = threadIdx.x;
  const int wave = tid >> 6, lane = tid & 63;
  const int l32 = lane & 31, hh = lane >> 5;
  const int sidx = blockIdx.x >> 5, bh = blockIdx.x & 31;
  const int b = bh >> 4, h = bh & 15;
  const size_t base = (size_t)b * T * C3;
  const int hD = h * 64;
  const int qb = 31 - sidx;            // big strips first (backfill order)
  const int nkt = (qb >> 1) + 1;
  const int tr = tid >> 3, kch = tid & 7;
  const float sc = 0.125f * 1.4426950408889634f;  // D^-0.5 * log2(e)

  // Q regs (shared q rows across waves): qf[qc][m], B-frag col=l32, k=hh*8+j
  bf16x8 qf[2][4];
#pragma unroll
  for (int qc = 0; qc < 2; ++qc)
#pragma unroll
    for (int m = 0; m < 4; ++m)
      qf[qc][m] = *(const bf16x8*)&kqv[base + (size_t)(qb * 64 + qc * 32 + l32) * C3 + C + hD + m * 16 + hh * 8];

  f32x16 o[2][2] = {};   // [qc][db]: O[q=qc*32+(r&3)+8*(r>>2)+4*hh][d=db*32+l32]
  float m_i[2] = {-1e30f, -1e30f}, l_i[2] = {0.f, 0.f};

  // prefetch tile 0 into VGPRs
  bf16x8 pk[4], pv0[2], pv1[2];
#pragma unroll
  for (int rr = 0; rr < 4; ++rr)
    pk[rr] = *(const bf16x8*)&kqv[base + (size_t)(rr * 32 + tr) * C3 + hD + kch * 8];
#pragma unroll
  for (int s2 = 0; s2 < 2; ++s2) {
    const size_t gg = base + (size_t)(2 * (s2 * 32 + tr)) * C3 + 2 * C + hD + kch * 8;
    pv0[s2] = *(const bf16x8*)&kqv[gg];
    pv1[s2] = *(const bf16x8*)&kqv[gg + C3];
  }

  for (int kt = 0; kt < nkt; ++kt) {
    __syncthreads();   // S1: prior tile's KP/Vt reads done
    // stage K from prefetch regs (b128, LDS addr loop-invariant)
#pragma unroll
    for (int rr = 0; rr < 4; ++rr)
      *(bf16x8*)&KP[(rr * 32 + tr) * 72 + kch * 8] = pk[rr];
    // stage V transposed: v_perm pack key-pairs, rot-16 swizzle
#pragma unroll
    for (int s2 = 0; s2 < 2; ++s2) {
      const int colw = ((s2 * 32 + tr) + 8 * kch) & 63;
      const uint32_t* a0 = (const uint32_t*)&pv0[s2];
      const uint32_t* a1 = (const uint32_t*)&pv1[s2];
#pragma unroll
      for (int i = 0; i < 8; ++i) {
        const uint32_t w = (i & 1)
            ? __builtin_amdgcn_perm(a1[i >> 1], a0[i >> 1], 0x07060302u)
            : __builtin_amdgcn_perm(a1[i >> 1], a0[i >> 1], 0x05040100u);
        VtW[(kch * 8 + i) * 68 + colw] = w;
      }
    }
    __syncthreads();   // S2: staging visible
    // prefetch next tile (loads stay in flight across the compute phase)
    if (kt + 1 < nkt) {
      const int kb2 = (kt + 1) * 128;
#pragma unroll
      for (int rr = 0; rr < 4; ++rr)
        pk[rr] = *(const bf16x8*)&kqv[base + (size_t)(kb2 + rr * 32 + tr) * C3 + hD + kch * 8];
#pragma unroll
      for (int s2 = 0; s2 < 2; ++s2) {
        const size_t gg = base + (size_t)(kb2 + 2 * (s2 * 32 + tr)) * C3 + 2 * C + hD + kch * 8;
        pv0[s2] = *(const bf16x8*)&kqv[gg];
        pv1[s2] = *(const bf16x8*)&kqv[gg + C3];
      }
    }

    // wave w handles keys kt*128 + w*32 .. +31; skip if fully beyond strip
    const bool act = (kt * 128 + wave * 32) <= (qb * 64 + 63);  // wave-uniform
    if (act) {
      bf16x8 kf[4];
#pragma unroll
      for (int m = 0; m < 4; ++m)
        kf[m] = *(const bf16x8*)&KP[(wave * 32 + l32) * 72 + m * 16 + hh * 8];

#pragma unroll
      for (int qc = 0; qc < 2; ++qc) {
        // S^T = K·Q^T : 32 keys x 32 q; lane holds S^T[key(r,hh)][q=l32]
        f32x16 z = {};
#pragma unroll
        for (int m = 0; m < 4; ++m)
          z = __builtin_amdgcn_mfma_f32_32x32x16_bf16(kf[m], qf[qc][m], z, 0, 0, 0);
        if (kt == nkt - 1) {   // diagonal tile: elementwise causal mask
          const int key0 = kt * 128 + wave * 32;
          const int qg = qb * 64 + qc * 32 + l32;
#pragma unroll
          for (int r = 0; r < 16; ++r) {
            const int kg = key0 + (r & 3) + 8 * (r >> 2) + 4 * hh;
            if (kg > qg) z[r] = -1e30f;
          }
        }
        // online softmax over this wave's 32 keys (hh-pair exchange only)
        float mloc = -1e30f;
#pragma unroll
        for (int r = 0; r < 16; ++r) mloc = fmaxf(mloc, z[r]);
        mloc = fmaxf(mloc, __shfl_xor(mloc, 32, 64));
        // FLOOR: all-masked tiles give m_i = -3e4, so masked pe underflows
        // to 0 instead of hitting the fmaf-residual inf (see header note).
        const float pm = fmaxf(mloc * sc, -3.0e4f);
        if (__any(pm - m_i[qc] > 8.0f)) {   // defer-max: rescale only on big jumps
          const float mnew = fmaxf(m_i[qc], pm);
          const float alpha = exp2f(m_i[qc] - mnew);
#pragma unroll
          for (int r = 0; r < 16; ++r) {
            const float ar = __shfl(alpha, (r & 3) + 8 * (r >> 2) + 4 * hh, 64);
            o[qc][0][r] *= ar;
            o[qc][1][r] *= ar;
          }
          l_i[qc] *= alpha;
          m_i[qc] = mnew;
        }
        float rs = 0.f;
#pragma unroll
        for (int r = 0; r < 16; ++r) {
          const float pe = exp2f(fmaf(z[r], sc, -m_i[qc]));
          z[r] = pe;
          rs += pe;
        }
        rs += __shfl_xor(rs, 32, 64);
        l_i[qc] += rs;

        // O += P·V : pack P to bf16, lane-half exchange, 2 k-chunks
        uint32_t x0 = pkbf(z[0], z[1]),   x1 = pkbf(z[2], z[3]);
        uint32_t y0 = pkbf(z[4], z[5]),   y1 = pkbf(z[6], z[7]);
        uint32_t x2 = pkbf(z[8], z[9]),   x3 = pkbf(z[10], z[11]);
        uint32_t y2 = pkbf(z[12], z[13]), y3 = pkbf(z[14], z[15]);
        const uint32_t s0 = hh ? x0 : y0, s1 = hh ? x1 : y1;
        const uint32_t s2 = hh ? x2 : y2, s3 = hh ? x3 : y3;
        const uint32_t t0 = __shfl_xor(s0, 32, 64), t1 = __shfl_xor(s1, 32, 64);
        const uint32_t t2 = __shfl_xor(s2, 32, 64), t3 = __shfl_xor(s3, 32, 64);
#pragma unroll
        for (int cc = 0; cc < 2; ++cc) {
          union { bf16x8 v; uint32_t w[4]; } pa;
          if (cc == 0) {
            pa.w[0] = hh ? t0 : x0; pa.w[1] = hh ? t1 : x1;   // keys 8hh+0..3
            pa.w[2] = hh ? y0 : t0; pa.w[3] = hh ? y1 : t1;   // keys 8hh+4..7
          } else {
            pa.w[0] = hh ? t2 : x2; pa.w[1] = hh ? t3 : x3;
            pa.w[2] = hh ? y2 : t2; pa.w[3] = hh ? y3 : t3;
          }
#pragma unroll
          for (int db = 0; db < 2; ++db) {
            const int d = db * 32 + l32;
            const int col = (wave * 32 + cc * 16 + hh * 8 + 16 * (d >> 3)) & 127;
            const bf16x8 vf = *(const bf16x8*)&Vt[d * 136 + col];
            o[qc][db] = __builtin_amdgcn_mfma_f32_32x32x16_bf16(pa.v, vf, o[qc][db], 0, 0, 0);
          }
        }
      }
    }
  }

  // ---- in-block merge of 4 per-wave partials, one qc-half at a time ----
#pragma unroll
  for (int qc = 0; qc < 2; ++qc) {
    __syncthreads();   // tiles done (qc=0) / obuf reads done (qc=1)
    if (hh == 0) {
      mlb[wave * 64 + l32] = m_i[qc];
      mlb[wave * 64 + 32 + l32] = l_i[qc];
    }
#pragma unroll
    for (int r = 0; r < 16; ++r) {
      const int ql = (r & 3) + 8 * (r >> 2) + 4 * hh;
      const int bw = wave * 2112 + ql * 66 + l32;
      obuf[bw] = o[qc][0][r];
      obuf[bw + 32] = o[qc][1][r];
    }
    __syncthreads();
    // sum phase: thread = (row q = l32, col-block cb = wave*2+hh)
    float mw[4], lw[4];
#pragma unroll
    for (int w = 0; w < 4; ++w) {
      mw[w] = mlb[w * 64 + l32];
      lw[w] = mlb[w * 64 + 32 + l32];
    }
    const float M = fmaxf(fmaxf(mw[0], mw[1]), fmaxf(mw[2], mw[3]));
    float L = 0.f, ww[4];
#pragma unroll
    for (int w = 0; w < 4; ++w) { ww[w] = exp2f(mw[w] - M); L += lw[w] * ww[w]; }
    const float Li = 1.0f / L;
    const int cb = wave * 2 + hh;
    float acc[8] = {};
#pragma unroll
    for (int w = 0; w < 4; ++w)
#pragma unroll
      for (int p = 0; p < 4; ++p) {
        const float2 v = *(const float2*)&obuf[w * 2112 + l32 * 66 + cb * 8 + p * 2];
        acc[2 * p]     += v.x * ww[w];
        acc[2 * p + 1] += v.y * ww[w];
      }
    union { bf16x8 v; uint32_t w4[4]; } ov;
#pragma unroll
    for (int p = 0; p < 4; ++p)
      ov.w4[p] = pkbf(acc[2 * p] * Li, acc[2 * p + 1] * Li);
    *(bf16x8*)&attn[((size_t)b * T + qb * 64 + qc * 32 + l32) * C + hD + cb * 8] = ov.v;
  }
}

extern "C" void kernel_launch(void* const* d_in, const int* in_sizes, int n_in,
                              void* d_out, int out_size, void* d_ws, size_t ws_size,
                              hipStream_t stream) {
  const float* x      = (const float*)d_in[0];  // (2,2048,1024) fp32
  const float* w_attn = (const float*)d_in[1];  // (3072,1024)  fp32
  const float* b_attn = (const float*)d_in[2];  // (3072,)      fp32
  const float* w_proj = (const float*)d_in[3];  // (1024,1024)  fp32
  const float* b_proj = (const float*)d_in[4];  // (1024,)      fp32
  float* out = (float*)d_out;                   // (2,2048,1024) fp32

  // ws layout (bf16): xb | wab | wpb | kqv | attnb
  uint16_t* xb    = (uint16_t*)d_ws;                     // 4096*1024
  uint16_t* wab   = xb  + (size_t)4096 * 1024;           // 3072*1024
  uint16_t* wpb   = wab + (size_t)3072 * 1024;           // 1024*1024
  uint16_t* kqv   = wpb + (size_t)1024 * 1024;           // 4096*3072
  uint16_t* attnb = kqv + (size_t)4096 * 3072;           // 4096*1024

  dim3 blk(256, 1, 1);
  hipLaunchKernelGGL(cvt_all, dim3(8192), blk, 0, stream, x, w_attn, w_proj, xb, wab, wpb);

  hipLaunchKernelGGL((gemm_bt_bias<128, true>), dim3(3072 / 128, 4096 / 128, 1), blk, 0, stream,
                     xb, wab, b_attn, (void*)kqv, 4096, 3072, 1024);
  hipLaunchKernelGGL(attn_flash, dim3(1024, 1, 1), blk, 0, stream, kqv, attnb);
  hipLaunchKernelGGL((gemm_bt_bias<64, false>), dim3(1024 / 128, 4096 / 64, 1), blk, 0, stream,
                     attnb, wpb, b_proj, (void*)out, 4096, 1024, 1024);
}